// Round 1
// baseline (1846.293 us; speedup 1.0000x reference)
//
#include <hip/hip_runtime.h>
#include <math.h>

#define NN 50000
#define EE 800000
#define FF 128

constexpr int EPB  = 16;    // edges per block
constexpr int NPB  = 16;    // nodes per block
constexpr int FSTR = 260;   // feature tile row stride (257 padded to mult of 4)
constexpr int HSTR = 132;   // hidden tile row stride (128 padded to mult of 4)
constexpr float LN_EPS = 1e-5f;

__device__ __forceinline__ float silu_f(float v) {
    return v / (1.f + __expf(-v));
}

// -------------------- edge kernel --------------------
// One block = 16 edges. Thread j (0..127) owns output feature j.
__global__ __launch_bounds__(128) void edge_kernel(
    const float* __restrict__ x, const float* __restrict__ pos,
    const int* __restrict__ ei,
    const float* __restrict__ ew1, const float* __restrict__ eb1,
    const float* __restrict__ ew2, const float* __restrict__ eb2,
    const float* __restrict__ cw,  const float* __restrict__ cb,
    float* __restrict__ agg, float* __restrict__ delta)
{
    __shared__ __align__(16) float feat[EPB * FSTR];  // [e][k] k<128:x_row 128..255:x_col 256:dist2
    __shared__ __align__(16) float h1[EPB * HSTR];
    __shared__ int   rowS[EPB];
    __shared__ int   colS[EPB];
    __shared__ float diffS[EPB][3];
    __shared__ float sS[EPB];
    __shared__ float part[2][EPB];

    const int t  = threadIdx.x;
    const int e0 = blockIdx.x * EPB;

    // phase 1: indices + diff/dist2
    if (t < EPB) {
        int r = ei[e0 + t];
        int c = ei[EE + e0 + t];
        rowS[t] = r;
        colS[t] = c;
        float dx = pos[r*3+0] - pos[c*3+0];
        float dy = pos[r*3+1] - pos[c*3+1];
        float dz = pos[r*3+2] - pos[c*3+2];
        diffS[t][0] = dx; diffS[t][1] = dy; diffS[t][2] = dz;
        feat[t*FSTR + 256] = dx*dx + dy*dy + dz*dz;
    }
    __syncthreads();

    // phase 2: gather x rows into LDS tile. 16 edges x 64 float4 = 1024 float4.
    #pragma unroll
    for (int i = 0; i < 8; ++i) {
        int idx = i * 128 + t;          // 0..1023
        int e   = idx >> 6;             // /64
        int q   = idx & 63;             // 0..63: 0..31 row half, 32..63 col half
        int node = (q < 32) ? rowS[e] : colS[e];
        int qq   = q & 31;
        float4 v = *(const float4*)&x[(size_t)node * FF + qq * 4];
        *(float4*)&feat[e * FSTR + 4 * q] = v;
    }
    __syncthreads();

    // phase 3: GEMM1  h1 = silu(feat @ ew1 + eb1)   K = 257
    float acc[EPB];
    {
        float b = eb1[t];
        #pragma unroll
        for (int e = 0; e < EPB; ++e) acc[e] = b;
    }
    for (int k = 0; k < 256; k += 4) {
        float w0 = ew1[(k+0)*FF + t];
        float w1 = ew1[(k+1)*FF + t];
        float w2 = ew1[(k+2)*FF + t];
        float w3 = ew1[(k+3)*FF + t];
        #pragma unroll
        for (int e = 0; e < EPB; ++e) {
            float4 f = *(const float4*)&feat[e*FSTR + k];
            acc[e] = fmaf(f.x, w0, acc[e]);
            acc[e] = fmaf(f.y, w1, acc[e]);
            acc[e] = fmaf(f.z, w2, acc[e]);
            acc[e] = fmaf(f.w, w3, acc[e]);
        }
    }
    {
        float w = ew1[256*FF + t];
        #pragma unroll
        for (int e = 0; e < EPB; ++e)
            acc[e] = fmaf(feat[e*FSTR + 256], w, acc[e]);
    }
    #pragma unroll
    for (int e = 0; e < EPB; ++e) h1[e*HSTR + t] = silu_f(acc[e]);
    __syncthreads();

    // phase 4: GEMM2  msg = h1 @ ew2 + eb2   K = 128
    float msg[EPB];
    {
        float b = eb2[t];
        #pragma unroll
        for (int e = 0; e < EPB; ++e) msg[e] = b;
    }
    for (int k = 0; k < 128; k += 4) {
        float w0 = ew2[(k+0)*FF + t];
        float w1 = ew2[(k+1)*FF + t];
        float w2 = ew2[(k+2)*FF + t];
        float w3 = ew2[(k+3)*FF + t];
        #pragma unroll
        for (int e = 0; e < EPB; ++e) {
            float4 f = *(const float4*)&h1[e*HSTR + k];
            msg[e] = fmaf(f.x, w0, msg[e]);
            msg[e] = fmaf(f.y, w1, msg[e]);
            msg[e] = fmaf(f.z, w2, msg[e]);
            msg[e] = fmaf(f.w, w3, msg[e]);
        }
    }

    // phase 5: coord scale s[e] = tanh(msg . cw + cb), 128-lane reduction
    {
        float cwj = cw[t];
        #pragma unroll
        for (int e = 0; e < EPB; ++e) {
            float v = msg[e] * cwj;
            #pragma unroll
            for (int off = 32; off >= 1; off >>= 1) v += __shfl_down(v, off);
            if ((t & 63) == 0) part[t >> 6][e] = v;
        }
    }
    __syncthreads();
    if (t < EPB) sS[t] = tanhf(part[0][t] + part[1][t] + cb[0]);
    __syncthreads();

    // phase 6: scatter
    #pragma unroll
    for (int e = 0; e < EPB; ++e) {
        atomicAdd(&agg[(size_t)rowS[e] * FF + t], msg[e]);
    }
    if (t < EPB * 3) {
        int e = t / 3, d = t % 3;
        atomicAdd(&delta[(size_t)rowS[e] * 3 + d], sS[e] * diffS[e][d]);
    }
}

// -------------------- node kernel --------------------
__global__ __launch_bounds__(128) void node_kernel(
    const float* __restrict__ x, const float* __restrict__ pos,
    const float* __restrict__ agg, const float* __restrict__ delta,
    const float* __restrict__ nw1, const float* __restrict__ nb1,
    const float* __restrict__ nw2, const float* __restrict__ nb2,
    const float* __restrict__ gamma, const float* __restrict__ beta,
    float* __restrict__ xout, float* __restrict__ posout)
{
    __shared__ __align__(16) float a[NPB * HSTR];
    __shared__ __align__(16) float h1[NPB * HSTR];
    __shared__ float red[2][NPB][2];

    const int t  = threadIdx.x;
    const int n0 = blockIdx.x * NPB;

    // load agg tile: 16 nodes x 32 float4 = 512 float4
    #pragma unroll
    for (int i = 0; i < 4; ++i) {
        int idx = i * 128 + t;        // 0..511
        int e   = idx >> 5;
        int q   = idx & 31;
        *(float4*)&a[e*HSTR + q*4] =
            *(const float4*)&agg[((size_t)(n0 + e)) * FF + q*4];
    }
    __syncthreads();

    // GEMM1: h1 = silu(a @ nw1 + nb1)
    float acc[NPB];
    {
        float b = nb1[t];
        #pragma unroll
        for (int e = 0; e < NPB; ++e) acc[e] = b;
    }
    for (int k = 0; k < 128; k += 4) {
        float w0 = nw1[(k+0)*FF + t];
        float w1 = nw1[(k+1)*FF + t];
        float w2 = nw1[(k+2)*FF + t];
        float w3 = nw1[(k+3)*FF + t];
        #pragma unroll
        for (int e = 0; e < NPB; ++e) {
            float4 f = *(const float4*)&a[e*HSTR + k];
            acc[e] = fmaf(f.x, w0, acc[e]);
            acc[e] = fmaf(f.y, w1, acc[e]);
            acc[e] = fmaf(f.z, w2, acc[e]);
            acc[e] = fmaf(f.w, w3, acc[e]);
        }
    }
    #pragma unroll
    for (int e = 0; e < NPB; ++e) h1[e*HSTR + t] = silu_f(acc[e]);
    __syncthreads();

    // GEMM2: upd = h1 @ nw2 + nb2
    float upd[NPB];
    {
        float b = nb2[t];
        #pragma unroll
        for (int e = 0; e < NPB; ++e) upd[e] = b;
    }
    for (int k = 0; k < 128; k += 4) {
        float w0 = nw2[(k+0)*FF + t];
        float w1 = nw2[(k+1)*FF + t];
        float w2 = nw2[(k+2)*FF + t];
        float w3 = nw2[(k+3)*FF + t];
        #pragma unroll
        for (int e = 0; e < NPB; ++e) {
            float4 f = *(const float4*)&h1[e*HSTR + k];
            upd[e] = fmaf(f.x, w0, upd[e]);
            upd[e] = fmaf(f.y, w1, upd[e]);
            upd[e] = fmaf(f.z, w2, upd[e]);
            upd[e] = fmaf(f.w, w3, upd[e]);
        }
    }

    // residual + LayerNorm
    #pragma unroll
    for (int e = 0; e < NPB; ++e) {
        float pre = x[((size_t)(n0 + e)) * FF + t] + upd[e];
        float s  = pre;
        float s2 = pre * pre;
        #pragma unroll
        for (int off = 32; off >= 1; off >>= 1) {
            s  += __shfl_down(s,  off);
            s2 += __shfl_down(s2, off);
        }
        if ((t & 63) == 0) { red[t >> 6][e][0] = s; red[t >> 6][e][1] = s2; }
        upd[e] = pre;   // stash pre
    }
    __syncthreads();

    {
        float g = gamma[t], b = beta[t];
        #pragma unroll
        for (int e = 0; e < NPB; ++e) {
            float mean = (red[0][e][0] + red[1][e][0]) * (1.f / FF);
            float m2   = (red[0][e][1] + red[1][e][1]) * (1.f / FF);
            float var  = m2 - mean * mean;
            float xo   = g * (upd[e] - mean) * rsqrtf(var + LN_EPS) + b;
            xout[((size_t)(n0 + e)) * FF + t] = xo;
        }
    }

    // pos update
    if (t < NPB * 3) {
        int e = t / 3, d = t % 3;
        size_t n = (size_t)(n0 + e);
        posout[n*3 + d] = pos[n*3 + d] + delta[n*3 + d];
    }
}

// -------------------- launcher --------------------
extern "C" void kernel_launch(void* const* d_in, const int* in_sizes, int n_in,
                              void* d_out, int out_size, void* d_ws, size_t ws_size,
                              hipStream_t stream) {
    const float* x    = (const float*)d_in[0];
    const float* pos  = (const float*)d_in[1];
    const int*   ei   = (const int*)  d_in[2];
    const float* ew1  = (const float*)d_in[3];
    const float* eb1  = (const float*)d_in[4];
    const float* ew2  = (const float*)d_in[5];
    const float* eb2  = (const float*)d_in[6];
    const float* nw1  = (const float*)d_in[7];
    const float* nb1  = (const float*)d_in[8];
    const float* nw2  = (const float*)d_in[9];
    const float* nb2  = (const float*)d_in[10];
    const float* cw   = (const float*)d_in[11];
    const float* cb   = (const float*)d_in[12];
    const float* gam  = (const float*)d_in[13];
    const float* bet  = (const float*)d_in[14];

    float* out    = (float*)d_out;
    float* xout   = out;                         // N*F
    float* posout = out + (size_t)NN * FF;       // N*3

    float* agg   = (float*)d_ws;                 // N*F
    float* delta = agg + (size_t)NN * FF;        // N*3

    hipMemsetAsync(d_ws, 0, ((size_t)NN * FF + (size_t)NN * 3) * sizeof(float), stream);

    edge_kernel<<<EE / EPB, 128, 0, stream>>>(
        x, pos, ei, ew1, eb1, ew2, eb2, cw, cb, agg, delta);

    node_kernel<<<NN / NPB, 128, 0, stream>>>(
        x, pos, agg, delta, nw1, nb1, nw2, nb2, gam, bet, xout, posout);
}

// Round 2
// 867.263 us; speedup vs baseline: 2.1289x; 2.1289x over previous
//
#include <hip/hip_runtime.h>
#include <math.h>

#define NN 50000
#define EE 800000
#define FF 128

constexpr float LN_EPS = 1e-5f;

typedef float  f32x4  __attribute__((ext_vector_type(4)));
typedef short  s16x8  __attribute__((ext_vector_type(8)));

__device__ __forceinline__ float silu_f(float v) {
    return v / (1.f + __expf(-v));
}

__device__ __forceinline__ unsigned short f2bf(float f) {
    union { float f; unsigned u; } cv; cv.f = f;
    unsigned u = cv.u;
    u += 0x7fffu + ((u >> 16) & 1u);   // round-to-nearest-even
    return (unsigned short)(u >> 16);
}

// -------------------- prep: x -> bf16 --------------------
__global__ __launch_bounds__(256) void convert_x_kernel(
    const float* __restrict__ x, unsigned short* __restrict__ xb)
{
    int i = (blockIdx.x * 256 + threadIdx.x) * 8;   // 8 elems/thread
    float4 a = *(const float4*)&x[i];
    float4 b = *(const float4*)&x[i + 4];
    s16x8 o;
    o[0] = (short)f2bf(a.x); o[1] = (short)f2bf(a.y);
    o[2] = (short)f2bf(a.z); o[3] = (short)f2bf(a.w);
    o[4] = (short)f2bf(b.x); o[5] = (short)f2bf(b.y);
    o[6] = (short)f2bf(b.z); o[7] = (short)f2bf(b.w);
    *(s16x8*)&xb[i] = o;
}

// -------------------- prep: transpose weights -> bf16 --------------------
// ew1T[n][k] = ew1[k][n]  (k<256, 128x256),  ew2T[n][k] = ew2[k][n] (128x128)
__global__ __launch_bounds__(256) void transpose_w_kernel(
    const float* __restrict__ ew1, const float* __restrict__ ew2,
    unsigned short* __restrict__ ew1T, unsigned short* __restrict__ ew2T)
{
    int o = blockIdx.x * 256 + threadIdx.x;
    if (o < 128 * 256) {
        int n = o >> 8, k = o & 255;
        ew1T[o] = f2bf(ew1[k * FF + n]);
    } else {
        int o2 = o - 128 * 256;
        int n = o2 >> 7, k = o2 & 127;
        ew2T[o2] = f2bf(ew2[k * FF + n]);
    }
}

// -------------------- edge kernel (MFMA bf16) --------------------
// Block: 256 threads = 4 waves, 32 edges. Wave w: edge half h=w&1,
// feature half qq=w>>1 (64 features as 4 tiles of 16).
constexpr int EPB = 32;
constexpr int H1S = 136;   // h1 LDS row stride in bf16 (128 + 8 pad)

__global__ __launch_bounds__(256) void edge_kernel(
    const unsigned short* __restrict__ xb, const float* __restrict__ pos,
    const int* __restrict__ ei,
    const unsigned short* __restrict__ ew1T, const float* __restrict__ ew1,  // ew1 for row 256
    const float* __restrict__ eb1,
    const unsigned short* __restrict__ ew2T, const float* __restrict__ eb2,
    const float* __restrict__ cw,  const float* __restrict__ cb,
    float* __restrict__ agg, float* __restrict__ delta)
{
    __shared__ int   rowS[EPB];
    __shared__ int   colS[EPB];
    __shared__ float diffS[EPB][3];
    __shared__ float dist2S[EPB];
    __shared__ float sPart[2][EPB];
    __shared__ float sS[EPB];
    __shared__ __align__(16) unsigned short h1[EPB * H1S];

    const int t   = threadIdx.x;
    const int w   = t >> 6;
    const int l   = t & 63;
    const int h   = w & 1;        // edge half
    const int qq  = w >> 1;       // feature half
    const int l15 = l & 15;
    const int q8  = l >> 4;       // quad 0..3
    const int e0  = blockIdx.x * EPB;

    // phase A: indices, diff, dist2
    if (t < EPB) {
        int r = ei[e0 + t];
        int c = ei[EE + e0 + t];
        rowS[t] = r;
        colS[t] = c;
        float dx = pos[r*3+0] - pos[c*3+0];
        float dy = pos[r*3+1] - pos[c*3+1];
        float dz = pos[r*3+2] - pos[c*3+2];
        diffS[t][0] = dx; diffS[t][1] = dy; diffS[t][2] = dz;
        dist2S[t] = dx*dx + dy*dy + dz*dz;
    }
    __syncthreads();

    // per-lane A-row pointers (m = h*16 + l15)
    const int m = h * 16 + l15;
    const unsigned short* aRow = xb + (size_t)rowS[m] * FF;
    const unsigned short* aCol = xb + (size_t)colS[m] * FF;

    // feature columns for the 4 tiles
    int ncol[4];
    #pragma unroll
    for (int tt = 0; tt < 4; ++tt) ncol[tt] = qq * 64 + tt * 16 + l15;

    // phase B: GEMM1  (32 edges x 128 feats, K=256) + dist2 rank-1 + bias + SiLU
    f32x4 acc[4] = {};
    #pragma unroll
    for (int ko = 0; ko < 8; ++ko) {
        const unsigned short* ap = (ko < 4 ? aRow : aCol) + ((ko & 3) * 32 + q8 * 8);
        s16x8 a = *(const s16x8*)ap;
        #pragma unroll
        for (int tt = 0; tt < 4; ++tt) {
            s16x8 b = *(const s16x8*)(ew1T + (size_t)ncol[tt] * 256 + ko * 32 + q8 * 8);
            acc[tt] = __builtin_amdgcn_mfma_f32_16x16x32_bf16(a, b, acc[tt], 0, 0, 0);
        }
    }
    #pragma unroll
    for (int tt = 0; tt < 4; ++tt) {
        int   n    = ncol[tt];
        float w256 = ew1[256 * FF + n];
        float b1   = eb1[n];
        #pragma unroll
        for (int r = 0; r < 4; ++r) {
            int e = h * 16 + q8 * 4 + r;
            float v = acc[tt][r] + dist2S[e] * w256 + b1;
            h1[e * H1S + n] = f2bf(silu_f(v));
        }
    }
    __syncthreads();

    // phase C: GEMM2 (K=128)
    f32x4 acc2[4] = {};
    const unsigned short* hrow = h1 + (h * 16 + l15) * H1S;
    #pragma unroll
    for (int ko = 0; ko < 4; ++ko) {
        s16x8 a = *(const s16x8*)(hrow + ko * 32 + q8 * 8);
        #pragma unroll
        for (int tt = 0; tt < 4; ++tt) {
            s16x8 b = *(const s16x8*)(ew2T + (size_t)ncol[tt] * 128 + ko * 32 + q8 * 8);
            acc2[tt] = __builtin_amdgcn_mfma_f32_16x16x32_bf16(a, b, acc2[tt], 0, 0, 0);
        }
    }
    float msg[4][4];
    #pragma unroll
    for (int tt = 0; tt < 4; ++tt) {
        float b2 = eb2[ncol[tt]];
        #pragma unroll
        for (int r = 0; r < 4; ++r) msg[tt][r] = acc2[tt][r] + b2;
    }

    // phase D: coord scale s[e] = tanh(msg . cw + cb)
    {
        float cwc[4];
        #pragma unroll
        for (int tt = 0; tt < 4; ++tt) cwc[tt] = cw[ncol[tt]];
        #pragma unroll
        for (int r = 0; r < 4; ++r) {
            float p = msg[0][r]*cwc[0] + msg[1][r]*cwc[1] + msg[2][r]*cwc[2] + msg[3][r]*cwc[3];
            #pragma unroll
            for (int off = 1; off < 16; off <<= 1) p += __shfl_xor(p, off);
            if (l15 == 0) sPart[qq][h * 16 + q8 * 4 + r] = p;
        }
    }
    __syncthreads();
    if (t < EPB) sS[t] = tanhf(sPart[0][t] + sPart[1][t] + cb[0]);
    __syncthreads();

    // phase E: scatter
    #pragma unroll
    for (int r = 0; r < 4; ++r) {
        int e = h * 16 + q8 * 4 + r;
        float* base = agg + (size_t)rowS[e] * FF;
        #pragma unroll
        for (int tt = 0; tt < 4; ++tt)
            atomicAdd(base + ncol[tt], msg[tt][r]);
    }
    if (t < EPB * 3) {
        int e = t / 3, d = t % 3;
        atomicAdd(&delta[(size_t)rowS[e] * 3 + d], sS[e] * diffS[e][d]);
    }
}

// -------------------- node kernel (f32, unchanged from R1) --------------------
constexpr int NPB  = 16;
constexpr int HSTR = 132;

__global__ __launch_bounds__(128) void node_kernel(
    const float* __restrict__ x, const float* __restrict__ pos,
    const float* __restrict__ agg, const float* __restrict__ delta,
    const float* __restrict__ nw1, const float* __restrict__ nb1,
    const float* __restrict__ nw2, const float* __restrict__ nb2,
    const float* __restrict__ gamma, const float* __restrict__ beta,
    float* __restrict__ xout, float* __restrict__ posout)
{
    __shared__ __align__(16) float a[NPB * HSTR];
    __shared__ __align__(16) float h1[NPB * HSTR];
    __shared__ float red[2][NPB][2];

    const int t  = threadIdx.x;
    const int n0 = blockIdx.x * NPB;

    #pragma unroll
    for (int i = 0; i < 4; ++i) {
        int idx = i * 128 + t;
        int e   = idx >> 5;
        int q   = idx & 31;
        *(float4*)&a[e*HSTR + q*4] =
            *(const float4*)&agg[((size_t)(n0 + e)) * FF + q*4];
    }
    __syncthreads();

    float acc[NPB];
    {
        float b = nb1[t];
        #pragma unroll
        for (int e = 0; e < NPB; ++e) acc[e] = b;
    }
    for (int k = 0; k < 128; k += 4) {
        float w0 = nw1[(k+0)*FF + t];
        float w1 = nw1[(k+1)*FF + t];
        float w2 = nw1[(k+2)*FF + t];
        float w3 = nw1[(k+3)*FF + t];
        #pragma unroll
        for (int e = 0; e < NPB; ++e) {
            float4 f = *(const float4*)&a[e*HSTR + k];
            acc[e] = fmaf(f.x, w0, acc[e]);
            acc[e] = fmaf(f.y, w1, acc[e]);
            acc[e] = fmaf(f.z, w2, acc[e]);
            acc[e] = fmaf(f.w, w3, acc[e]);
        }
    }
    #pragma unroll
    for (int e = 0; e < NPB; ++e) h1[e*HSTR + t] = silu_f(acc[e]);
    __syncthreads();

    float upd[NPB];
    {
        float b = nb2[t];
        #pragma unroll
        for (int e = 0; e < NPB; ++e) upd[e] = b;
    }
    for (int k = 0; k < 128; k += 4) {
        float w0 = nw2[(k+0)*FF + t];
        float w1 = nw2[(k+1)*FF + t];
        float w2 = nw2[(k+2)*FF + t];
        float w3 = nw2[(k+3)*FF + t];
        #pragma unroll
        for (int e = 0; e < NPB; ++e) {
            float4 f = *(const float4*)&h1[e*HSTR + k];
            upd[e] = fmaf(f.x, w0, upd[e]);
            upd[e] = fmaf(f.y, w1, upd[e]);
            upd[e] = fmaf(f.z, w2, upd[e]);
            upd[e] = fmaf(f.w, w3, upd[e]);
        }
    }

    #pragma unroll
    for (int e = 0; e < NPB; ++e) {
        float pre = x[((size_t)(n0 + e)) * FF + t] + upd[e];
        float s  = pre;
        float s2 = pre * pre;
        #pragma unroll
        for (int off = 32; off >= 1; off >>= 1) {
            s  += __shfl_down(s,  off);
            s2 += __shfl_down(s2, off);
        }
        if ((t & 63) == 0) { red[t >> 6][e][0] = s; red[t >> 6][e][1] = s2; }
        upd[e] = pre;
    }
    __syncthreads();

    {
        float g = gamma[t], b = beta[t];
        #pragma unroll
        for (int e = 0; e < NPB; ++e) {
            float mean = (red[0][e][0] + red[1][e][0]) * (1.f / FF);
            float m2   = (red[0][e][1] + red[1][e][1]) * (1.f / FF);
            float var  = m2 - mean * mean;
            float xo   = g * (upd[e] - mean) * rsqrtf(var + LN_EPS) + b;
            xout[((size_t)(n0 + e)) * FF + t] = xo;
        }
    }

    if (t < NPB * 3) {
        int e = t / 3, d = t % 3;
        size_t n = (size_t)(n0 + e);
        posout[n*3 + d] = pos[n*3 + d] + delta[n*3 + d];
    }
}

// -------------------- launcher --------------------
extern "C" void kernel_launch(void* const* d_in, const int* in_sizes, int n_in,
                              void* d_out, int out_size, void* d_ws, size_t ws_size,
                              hipStream_t stream) {
    const float* x    = (const float*)d_in[0];
    const float* pos  = (const float*)d_in[1];
    const int*   ei   = (const int*)  d_in[2];
    const float* ew1  = (const float*)d_in[3];
    const float* eb1  = (const float*)d_in[4];
    const float* ew2  = (const float*)d_in[5];
    const float* eb2  = (const float*)d_in[6];
    const float* nw1  = (const float*)d_in[7];
    const float* nb1  = (const float*)d_in[8];
    const float* nw2  = (const float*)d_in[9];
    const float* nb2  = (const float*)d_in[10];
    const float* cw   = (const float*)d_in[11];
    const float* cb   = (const float*)d_in[12];
    const float* gam  = (const float*)d_in[13];
    const float* bet  = (const float*)d_in[14];

    float* out    = (float*)d_out;
    float* xout   = out;
    float* posout = out + (size_t)NN * FF;

    // workspace layout (256B-aligned chunks)
    char* ws = (char*)d_ws;
    size_t AGG_B   = (size_t)NN * FF * 4;          // 25,600,000
    size_t DELTA_B = ((size_t)NN * 3 * 4 + 255) & ~(size_t)255;
    float*          agg   = (float*)ws;
    float*          delta = (float*)(ws + AGG_B);
    unsigned short* xb    = (unsigned short*)(ws + AGG_B + DELTA_B);
    unsigned short* ew1T  = xb + (size_t)NN * FF;
    unsigned short* ew2T  = ew1T + 128 * 256;

    hipMemsetAsync(ws, 0, AGG_B + (size_t)NN * 3 * 4, stream);

    convert_x_kernel<<<(NN * FF / 8) / 256, 256, 0, stream>>>(x, xb);
    transpose_w_kernel<<<(128 * 256 + 128 * 128) / 256, 256, 0, stream>>>(ew1, ew2, ew1T, ew2T);

    edge_kernel<<<EE / EPB, 256, 0, stream>>>(
        xb, pos, ei, ew1T, ew1, eb1, ew2T, eb2, cw, cb, agg, delta);

    node_kernel<<<NN / NPB, 128, 0, stream>>>(
        x, pos, agg, delta, nw1, nb1, nw2, nb2, gam, bet, xout, posout);
}